// Round 16
// baseline (512.544 us; speedup 1.0000x reference)
//
#include <hip/hip_runtime.h>
#include <hip/hip_bf16.h>
#include <cstdint>
#include <cstddef>

typedef __attribute__((ext_vector_type(8))) short bf16x8;
typedef __attribute__((ext_vector_type(4))) short bf16x4;
typedef __attribute__((ext_vector_type(4))) float f32x4;
typedef __attribute__((ext_vector_type(16))) float f32x16;

#define GLB_AS(p) ((const __attribute__((address_space(1))) void*)(p))
#define LDS_AS(p) ((__attribute__((address_space(3))) void*)(p))

__device__ __forceinline__ short f2bf(float f) {
    union { float f; unsigned u; } x; x.f = f;
    unsigned r = (x.u + 0x7fffu + ((x.u >> 16) & 1u)) >> 16;
    return (short)r;
}
__device__ __forceinline__ float bf2f(short s) {
    union { unsigned u; float f; } x;
    x.u = ((unsigned)(unsigned short)s) << 16;
    return x.f;
}
__device__ __forceinline__ unsigned packbf2(float a, float b) {
    union { float f; unsigned u; } x, y; x.f = a; y.f = b;
    return (x.u >> 16) | (y.u & 0xffff0000u);
}
__device__ __forceinline__ f32x4 MF(bf16x8 a, bf16x8 b, f32x4 c) {
    return __builtin_amdgcn_mfma_f32_16x16x32_bf16(a, b, c, 0, 0, 0);
}
__device__ __forceinline__ f32x16 MF32(bf16x8 a, bf16x8 b, f32x16 c) {
    return __builtin_amdgcn_mfma_f32_32x32x16_bf16(a, b, c, 0, 0, 0);
}

// ---------------- fused: LN1 (one row/block) + weight-cast slice ----------------
__global__ __launch_bounds__(256) void k_prep(const float* __restrict__ x,
                                              const float* __restrict__ ln1_w,
                                              const float* __restrict__ ln1_b,
                                              short* __restrict__ xhat,
                                              const float* __restrict__ s0,
                                              const float* __restrict__ s1,
                                              const float* __restrict__ s2,
                                              const float* __restrict__ s3,
                                              short* __restrict__ d0,
                                              short* __restrict__ d1,
                                              short* __restrict__ d2,
                                              short* __restrict__ d3,
                                              int n0, int n1, int n2, int n3) {
    const int row = blockIdx.x;
    const int tid = threadIdx.x;
    {
        const float* xr = x + (size_t)row * 768;
        float v0 = xr[tid], v1 = xr[tid + 256], v2 = xr[tid + 512];
        float s = v0 + v1 + v2;
        float ss = v0 * v0 + v1 * v1 + v2 * v2;
        #pragma unroll
        for (int m = 32; m; m >>= 1) { s += __shfl_xor(s, m); ss += __shfl_xor(ss, m); }
        __shared__ float red[8];
        int wid = tid >> 6, lane = tid & 63;
        if (lane == 0) { red[wid] = s; red[4 + wid] = ss; }
        __syncthreads();
        s = red[0] + red[1] + red[2] + red[3];
        ss = red[4] + red[5] + red[6] + red[7];
        float mean = s * (1.f / 768.f);
        float var = ss * (1.f / 768.f) - mean * mean;
        float inv = rsqrtf(var + 1e-5f);
        short* orow = xhat + (size_t)row * 768;
        orow[tid]       = f2bf((v0 - mean) * inv * ln1_w[tid]       + ln1_b[tid]);
        orow[tid + 256] = f2bf((v1 - mean) * inv * ln1_w[tid + 256] + ln1_b[tid + 256]);
        orow[tid + 512] = f2bf((v2 - mean) * inv * ln1_w[tid + 512] + ln1_b[tid + 512]);
    }
    const int total = n0 + n1 + n2 + n3;
    const int stride = gridDim.x * 256;
    for (int i = blockIdx.x * 256 + tid; i < total; i += stride) {
        int j = i;
        const float* s; short* d;
        if (j < n0) { s = s0; d = d0; }
        else {
            j -= n0;
            if (j < n1) { s = s1; d = d1; }
            else {
                j -= n1;
                if (j < n2) { s = s2; d = d2; }
                else { j -= n2; s = s3; d = d3; }
            }
        }
        float4 v = ((const float4*)s)[j];
        bf16x4 o;
        o[0] = f2bf(v.x); o[1] = f2bf(v.y); o[2] = f2bf(v.z); o[3] = f2bf(v.w);
        ((bf16x4*)d)[j] = o;
    }
}

// ---------------- LayerNorm on bf16 input (x2) -> bf16 ----------------
__global__ __launch_bounds__(256) void k_layernorm_bf(const short* __restrict__ xb,
                                                      const float* __restrict__ w,
                                                      const float* __restrict__ b,
                                                      short* __restrict__ out) {
    const int row = blockIdx.x;
    const int tid = threadIdx.x;
    float v[4] = {0.f, 0.f, 0.f, 0.f};
    if (tid < 192) {
        bf16x4 raw = ((const bf16x4*)(xb + (size_t)row * 768))[tid];
        #pragma unroll
        for (int j = 0; j < 4; ++j) v[j] = bf2f(raw[j]);
    }
    float s = v[0] + v[1] + v[2] + v[3];
    float ss = v[0] * v[0] + v[1] * v[1] + v[2] * v[2] + v[3] * v[3];
    #pragma unroll
    for (int m = 32; m; m >>= 1) { s += __shfl_xor(s, m); ss += __shfl_xor(ss, m); }
    __shared__ float red[8];
    int wid = tid >> 6, lane = tid & 63;
    if (lane == 0) { red[wid] = s; red[4 + wid] = ss; }
    __syncthreads();
    s = red[0] + red[1] + red[2] + red[3];
    ss = red[4] + red[5] + red[6] + red[7];
    float mean = s * (1.f / 768.f);
    float var = ss * (1.f / 768.f) - mean * mean;
    float inv = rsqrtf(var + 1e-5f);
    if (tid < 192) {
        float4 wv = ((const float4*)w)[tid];
        float4 bv = ((const float4*)b)[tid];
        bf16x4 o;
        o[0] = f2bf((v[0] - mean) * inv * wv.x + bv.x);
        o[1] = f2bf((v[1] - mean) * inv * wv.y + bv.y);
        o[2] = f2bf((v[2] - mean) * inv * wv.z + bv.z);
        o[3] = f2bf((v[3] - mean) * inv * wv.w + bv.w);
        ((bf16x4*)(out + (size_t)row * 768))[tid] = o;
    }
}

// ============ 256 x (NFR*64) GEMM (16x16 MFMA), R11-proven schedule ============
// EPI 0: bf16 = acc+bias | 2: bf16 gelu(acc+bias) | 3: bf16 = acc+bias+f32res
// EPI 4: f32 = acc+bias+bf16res
template <int EPI, int NFR>
__global__ __launch_bounds__(512, 2) void k_gemm256(const short* __restrict__ A,
                                                    const short* __restrict__ B,
                                                    const float* __restrict__ bias,
                                                    const void* __restrict__ res,
                                                    void* __restrict__ out,
                                                    int M, int N, int K) {
    __shared__ short As2[2][256 * 64];
    __shared__ short Bs2[2][NFR * 64 * 64];
    const int tid = threadIdx.x, lane = tid & 63, wid = tid >> 6;
    const int l4 = lane & 15, lh = lane >> 4;
    const int wm = wid >> 2, wn = wid & 3;
    const int gx = gridDim.x;
    const int nwg = gx * gridDim.y;
    int wg = blockIdx.y * gx + blockIdx.x;
    { const int q = nwg >> 3; wg = (wg & 7) * q + (wg >> 3); }   // nwg % 8 == 0
    const int row0 = (wg / gx) * 256, col0 = (wg % gx) * (NFR * 64);

    auto stageA = [&](short* lds, int mh, int k0) {
        #pragma unroll
        for (int i = 0; i < 2; ++i) {
            const int chunk = wid * 2 + i;
            const int dl = mh * 16384 + chunk * 1024 + lane * 16;
            const int r = dl >> 7;
            const int cb = (dl & 127) ^ ((r & 7) << 4);
            __builtin_amdgcn_global_load_lds(
                GLB_AS(A + (size_t)(row0 + r) * K + k0 + (cb >> 1)),
                LDS_AS(lds + mh * 8192 + chunk * 512), 16, 0, 0);
        }
    };
    auto stageB = [&](short* lds, int k0) {
        #pragma unroll
        for (int i = 0; i < NFR; ++i) {
            const int chunk = wid * NFR + i;
            const int dl = chunk * 1024 + lane * 16;
            const int r = dl >> 7;
            const int cb = (dl & 127) ^ ((r & 7) << 4);
            __builtin_amdgcn_global_load_lds(
                GLB_AS(B + (size_t)(col0 + r) * K + k0 + (cb >> 1)),
                LDS_AS(lds + chunk * 512), 16, 0, 0);
        }
    };
    auto rd = [&](const short* lds, int r, int kb) -> bf16x8 {
        return *(const bf16x8*)((const char*)lds + r * 128 +
                                ((kb * 64 + lh * 16) ^ ((r & 7) << 4)));
    };

    f32x4 acc[8][NFR] = {};
    bf16x8 a[4][2], b0[2][2], b1[2][2];
    const int NT = K >> 6;

    stageA(As2[0], 0, 0);
    stageA(As2[0], 1, 0);
    stageB(Bs2[0], 0);
    asm volatile("s_waitcnt vmcnt(0)" ::: "memory");
    __builtin_amdgcn_s_barrier();

    for (int t = 0; t < NT; ++t) {
        const int cur = t & 1, nxt = cur ^ 1;
        const short* Ac = As2[cur];
        const short* Bc = Bs2[cur];
        const int kn = (t + 1) << 6;
        const bool more = (t + 1 < NT);
        #pragma unroll
        for (int mi = 0; mi < 4; ++mi) {
            const int r = wm * 128 + mi * 16 + l4;
            a[mi][0] = rd(Ac, r, 0); a[mi][1] = rd(Ac, r, 1);
        }
        #pragma unroll
        for (int ni = 0; ni < 2; ++ni) {
            const int r = wn * (NFR * 16) + ni * 16 + l4;
            b0[ni][0] = rd(Bc, r, 0); b0[ni][1] = rd(Bc, r, 1);
        }
        if (more) { stageA(As2[nxt], 0, kn); stageA(As2[nxt], 1, kn); }
        __builtin_amdgcn_s_setprio(1);
        #pragma unroll
        for (int mi = 0; mi < 4; ++mi)
            #pragma unroll
            for (int ni = 0; ni < 2; ++ni) {
                acc[mi][ni] = MF(a[mi][0], b0[ni][0], acc[mi][ni]);
                acc[mi][ni] = MF(a[mi][1], b0[ni][1], acc[mi][ni]);
            }
        __builtin_amdgcn_s_setprio(0);
        __builtin_amdgcn_s_barrier();
        #pragma unroll
        for (int j = 0; j < NFR - 2; ++j) {
            const int r = wn * (NFR * 16) + (2 + j) * 16 + l4;
            b1[j][0] = rd(Bc, r, 0); b1[j][1] = rd(Bc, r, 1);
        }
        if (more) stageB(Bs2[nxt], kn);
        __builtin_amdgcn_s_setprio(1);
        #pragma unroll
        for (int mi = 0; mi < 4; ++mi)
            #pragma unroll
            for (int j = 0; j < NFR - 2; ++j) {
                acc[mi][2 + j] = MF(a[mi][0], b1[j][0], acc[mi][2 + j]);
                acc[mi][2 + j] = MF(a[mi][1], b1[j][1], acc[mi][2 + j]);
            }
        __builtin_amdgcn_s_setprio(0);
        __builtin_amdgcn_s_barrier();
        #pragma unroll
        for (int mi = 0; mi < 4; ++mi) {
            const int r = wm * 128 + (4 + mi) * 16 + l4;
            a[mi][0] = rd(Ac, r, 0); a[mi][1] = rd(Ac, r, 1);
        }
        __builtin_amdgcn_s_setprio(1);
        #pragma unroll
        for (int mi = 0; mi < 4; ++mi)
            #pragma unroll
            for (int j = 0; j < NFR - 2; ++j) {
                acc[4 + mi][2 + j] = MF(a[mi][0], b1[j][0], acc[4 + mi][2 + j]);
                acc[4 + mi][2 + j] = MF(a[mi][1], b1[j][1], acc[4 + mi][2 + j]);
            }
        __builtin_amdgcn_s_setprio(0);
        __builtin_amdgcn_s_barrier();
        __builtin_amdgcn_s_setprio(1);
        #pragma unroll
        for (int mi = 0; mi < 4; ++mi)
            #pragma unroll
            for (int ni = 0; ni < 2; ++ni) {
                acc[4 + mi][ni] = MF(a[mi][0], b0[ni][0], acc[4 + mi][ni]);
                acc[4 + mi][ni] = MF(a[mi][1], b0[ni][1], acc[4 + mi][ni]);
            }
        __builtin_amdgcn_s_setprio(0);
        if (more) asm volatile("s_waitcnt vmcnt(0)" ::: "memory");
        __builtin_amdgcn_s_barrier();
    }

    #pragma unroll
    for (int mi = 0; mi < 8; ++mi) {
        const int rowb = row0 + wm * 128 + mi * 16 + lh * 4;
        #pragma unroll
        for (int ni = 0; ni < NFR; ++ni) {
            const int col = col0 + wn * (NFR * 16) + ni * 16 + l4;
            const float bv = bias[col];
            #pragma unroll
            for (int j = 0; j < 4; ++j) {
                const size_t idx = (size_t)(rowb + j) * N + col;
                float v = acc[mi][ni][j] + bv;
                if (EPI == 0) {
                    ((short*)out)[idx] = f2bf(v);
                } else if (EPI == 2) {
                    float u = v + 0.044715f * v * v * v;
                    float t = 1.f - 2.f / (__expf(1.5957691216f * u) + 1.f);
                    ((short*)out)[idx] = f2bf(0.5f * v * (1.f + t));
                } else if (EPI == 3) {
                    ((short*)out)[idx] = f2bf(v + ((const float*)res)[idx]);
                } else { // EPI == 4
                    ((float*)out)[idx] = v + bf2f(((const short*)res)[idx]);
                }
            }
        }
    }
}

// ============ fc: 256 x 384 GEMM (16x16 MFMA) — 512 blocks = 2 exact rounds ===
// 3+3 N-fragment split; b0 re-read from LDS in ph4 to cap register pressure.
// LDS 160 KB (2x(32KB A + 48KB B)). Same staging/swizzle/sync as k_gemm256.
template <int EPI>
__global__ __launch_bounds__(512, 2) void k_gemm384(const short* __restrict__ A,
                                                    const short* __restrict__ B,
                                                    const float* __restrict__ bias,
                                                    const void* __restrict__ res,
                                                    void* __restrict__ out,
                                                    int M, int N, int K) {
    __shared__ short As2[2][256 * 64];   // 64 KB
    __shared__ short Bs2[2][384 * 64];   // 96 KB
    const int tid = threadIdx.x, lane = tid & 63, wid = tid >> 6;
    const int l4 = lane & 15, lh = lane >> 4;
    const int wm = wid >> 2, wn = wid & 3;
    const int gx = gridDim.x;
    const int nwg = gx * gridDim.y;
    int wg = blockIdx.y * gx + blockIdx.x;
    { const int q = nwg >> 3; wg = (wg & 7) * q + (wg >> 3); }   // nwg % 8 == 0
    const int row0 = (wg / gx) * 256, col0 = (wg % gx) * 384;

    auto stageA = [&](short* lds, int mh, int k0) {
        #pragma unroll
        for (int i = 0; i < 2; ++i) {
            const int chunk = wid * 2 + i;
            const int dl = mh * 16384 + chunk * 1024 + lane * 16;
            const int r = dl >> 7;
            const int cb = (dl & 127) ^ ((r & 7) << 4);
            __builtin_amdgcn_global_load_lds(
                GLB_AS(A + (size_t)(row0 + r) * K + k0 + (cb >> 1)),
                LDS_AS(lds + mh * 8192 + chunk * 512), 16, 0, 0);
        }
    };
    auto stageB = [&](short* lds, int k0) {
        #pragma unroll
        for (int i = 0; i < 6; ++i) {
            const int chunk = wid * 6 + i;
            const int dl = chunk * 1024 + lane * 16;
            const int r = dl >> 7;
            const int cb = (dl & 127) ^ ((r & 7) << 4);
            __builtin_amdgcn_global_load_lds(
                GLB_AS(B + (size_t)(col0 + r) * K + k0 + (cb >> 1)),
                LDS_AS(lds + chunk * 512), 16, 0, 0);
        }
    };
    auto rd = [&](const short* lds, int r, int kb) -> bf16x8 {
        return *(const bf16x8*)((const char*)lds + r * 128 +
                                ((kb * 64 + lh * 16) ^ ((r & 7) << 4)));
    };

    f32x4 acc[8][6] = {};
    const int NT = K >> 6;

    stageA(As2[0], 0, 0);
    stageA(As2[0], 1, 0);
    stageB(Bs2[0], 0);
    asm volatile("s_waitcnt vmcnt(0)" ::: "memory");
    __builtin_amdgcn_s_barrier();

    for (int t = 0; t < NT; ++t) {
        const int cur = t & 1, nxt = cur ^ 1;
        const short* Ac = As2[cur];
        const short* Bc = Bs2[cur];
        const int kn = (t + 1) << 6;
        const bool more = (t + 1 < NT);
        bf16x8 a[4][2];
        // ph1: loM x N{0,1,2}; stage A both halves of t+1
        {
            bf16x8 b0[3][2];
            #pragma unroll
            for (int mi = 0; mi < 4; ++mi) {
                const int r = wm * 128 + mi * 16 + l4;
                a[mi][0] = rd(Ac, r, 0); a[mi][1] = rd(Ac, r, 1);
            }
            #pragma unroll
            for (int ni = 0; ni < 3; ++ni) {
                const int r = wn * 96 + ni * 16 + l4;
                b0[ni][0] = rd(Bc, r, 0); b0[ni][1] = rd(Bc, r, 1);
            }
            if (more) { stageA(As2[nxt], 0, kn); stageA(As2[nxt], 1, kn); }
            __builtin_amdgcn_s_setprio(1);
            #pragma unroll
            for (int mi = 0; mi < 4; ++mi)
                #pragma unroll
                for (int ni = 0; ni < 3; ++ni) {
                    acc[mi][ni] = MF(a[mi][0], b0[ni][0], acc[mi][ni]);
                    acc[mi][ni] = MF(a[mi][1], b0[ni][1], acc[mi][ni]);
                }
            __builtin_amdgcn_s_setprio(0);
        }
        __builtin_amdgcn_s_barrier();
        // ph2 + ph3 share b1
        {
            bf16x8 b1[3][2];
            #pragma unroll
            for (int j = 0; j < 3; ++j) {
                const int r = wn * 96 + (3 + j) * 16 + l4;
                b1[j][0] = rd(Bc, r, 0); b1[j][1] = rd(Bc, r, 1);
            }
            if (more) stageB(Bs2[nxt], kn);
            __builtin_amdgcn_s_setprio(1);
            #pragma unroll
            for (int mi = 0; mi < 4; ++mi)
                #pragma unroll
                for (int j = 0; j < 3; ++j) {
                    acc[mi][3 + j] = MF(a[mi][0], b1[j][0], acc[mi][3 + j]);
                    acc[mi][3 + j] = MF(a[mi][1], b1[j][1], acc[mi][3 + j]);
                }
            __builtin_amdgcn_s_setprio(0);
            __builtin_amdgcn_s_barrier();
            // ph3: hiM x N{3,4,5}
            #pragma unroll
            for (int mi = 0; mi < 4; ++mi) {
                const int r = wm * 128 + (4 + mi) * 16 + l4;
                a[mi][0] = rd(Ac, r, 0); a[mi][1] = rd(Ac, r, 1);
            }
            __builtin_amdgcn_s_setprio(1);
            #pragma unroll
            for (int mi = 0; mi < 4; ++mi)
                #pragma unroll
                for (int j = 0; j < 3; ++j) {
                    acc[4 + mi][3 + j] = MF(a[mi][0], b1[j][0], acc[4 + mi][3 + j]);
                    acc[4 + mi][3 + j] = MF(a[mi][1], b1[j][1], acc[4 + mi][3 + j]);
                }
            __builtin_amdgcn_s_setprio(0);
        }
        __builtin_amdgcn_s_barrier();
        // ph4: hiM x N{0,1,2} (b0 re-read); drain staging
        {
            bf16x8 b0b[3][2];
            #pragma unroll
            for (int ni = 0; ni < 3; ++ni) {
                const int r = wn * 96 + ni * 16 + l4;
                b0b[ni][0] = rd(Bc, r, 0); b0b[ni][1] = rd(Bc, r, 1);
            }
            __builtin_amdgcn_s_setprio(1);
            #pragma unroll
            for (int mi = 0; mi < 4; ++mi)
                #pragma unroll
                for (int ni = 0; ni < 3; ++ni) {
                    acc[4 + mi][ni] = MF(a[mi][0], b0b[ni][0], acc[4 + mi][ni]);
                    acc[4 + mi][ni] = MF(a[mi][1], b0b[ni][1], acc[4 + mi][ni]);
                }
            __builtin_amdgcn_s_setprio(0);
        }
        if (more) asm volatile("s_waitcnt vmcnt(0)" ::: "memory");
        __builtin_amdgcn_s_barrier();
    }

    #pragma unroll
    for (int mi = 0; mi < 8; ++mi) {
        const int rowb = row0 + wm * 128 + mi * 16 + lh * 4;
        #pragma unroll
        for (int ni = 0; ni < 6; ++ni) {
            const int col = col0 + wn * 96 + ni * 16 + l4;
            const float bv = bias[col];
            #pragma unroll
            for (int j = 0; j < 4; ++j) {
                const size_t idx = (size_t)(rowb + j) * N + col;
                float v = acc[mi][ni][j] + bv;
                if (EPI == 0) {
                    ((short*)out)[idx] = f2bf(v);
                } else if (EPI == 2) {
                    float u = v + 0.044715f * v * v * v;
                    float t = 1.f - 2.f / (__expf(1.5957691216f * u) + 1.f);
                    ((short*)out)[idx] = f2bf(0.5f * v * (1.f + t));
                } else if (EPI == 3) {
                    ((short*)out)[idx] = f2bf(v + ((const float*)res)[idx]);
                } else {
                    ((float*)out)[idx] = v + bf2f(((const short*)res)[idx]);
                }
            }
        }
    }
}

// ---------------- causal flash attention v8: merged q-tile pair (R11) ----------
#define ATTN_PROC(QF, O, LROW, QA, Q0)                                         \
    if (kv0 <= (Q0) + 31) {                                                    \
        const bool full = (kv0 + 63 <= (Q0));                                  \
        f32x16 s0 = {}, s1 = {};                                               \
        __builtin_amdgcn_s_setprio(1);                                         \
        _Pragma("unroll")                                                      \
        for (int kb = 0; kb < 6; ++kb) {                                       \
            const int r0 = lq, r1 = 32 + lq;                                   \
            bf16x8 kf0 = *(const bf16x8*)((const char*)&Ks[cur][0] +           \
                          r0 * 256 + ((kb * 32 + hi * 16) ^ ((r0 & 7) << 4))); \
            bf16x8 kf1 = *(const bf16x8*)((const char*)&Ks[cur][0] +           \
                          r1 * 256 + ((kb * 32 + hi * 16) ^ ((r1 & 7) << 4))); \
            s0 = MF32(kf0, QF[kb], s0);                                        \
            s1 = MF32(kf1, QF[kb], s1);                                        \
        }                                                                      \
        __builtin_amdgcn_s_setprio(0);                                         \
        if (!full) {                                                           \
            _Pragma("unroll")                                                  \
            for (int r = 0; r < 16; ++r) {                                     \
                const int kvl = (r & 3) + 8 * (r >> 2) + 4 * hi;               \
                if (kv0 + kvl > (QA)) s0[r] = -INFINITY;                       \
                if (kv0 + 32 + kvl > (QA)) s1[r] = -INFINITY;                  \
            }                                                                  \
        }                                                                      \
        _Pragma("unroll")                                                      \
        for (int r = 0; r < 16; ++r) { s0[r] = exp2f(s0[r]); s1[r] = exp2f(s1[r]); } \
        float ar[16];                                                          \
        _Pragma("unroll")                                                      \
        for (int r = 0; r < 16; ++r) ar[r] = s0[r] + s1[r];                    \
        _Pragma("unroll")                                                      \
        for (int st = 8; st; st >>= 1)                                         \
            _Pragma("unroll")                                                  \
            for (int r = 0; r < 8; ++r)                                        \
                if (r < st) ar[r] += ar[r + st];                               \
        (LROW) += ar[0] + __shfl_xor(ar[0], 32);                               \
        unsigned pk0[8], pk1[8];                                               \
        _Pragma("unroll")                                                      \
        for (int j = 0; j < 8; ++j) {                                          \
            pk0[j] = packbf2(s0[2 * j], s0[2 * j + 1]);                        \
            pk1[j] = packbf2(s1[2 * j], s1[2 * j + 1]);                        \
        }                                                                      \
        __builtin_amdgcn_s_setprio(1);                                         \
        _Pragma("unroll")                                                      \
        for (int db = 0; db < 3; ++db) {                                       \
            const int vrow = db * 32 + lq;                                     \
            const int vsw = ((vrow & 7) ^ ((vrow >> 3) & 7)) << 4;             \
            _Pragma("unroll")                                                  \
            for (int c = 0; c < 4; ++c) {                                      \
                bf16x8 vf = *(const bf16x8*)((const char*)&Vs[cur][0] +        \
                             vrow * 128 + ((c * 32 + hi * 16) ^ vsw));         \
                union { unsigned u[4]; bf16x8 v; } pa;                         \
                const unsigned* pk = (c < 2) ? pk0 : pk1;                      \
                const int o4 = (c & 1) * 4;                                    \
                pa.u[0] = pk[o4]; pa.u[1] = pk[o4 + 1];                        \
                pa.u[2] = pk[o4 + 2]; pa.u[3] = pk[o4 + 3];                    \
                (O)[db] = MF32(vf, pa.v, (O)[db]);                             \
            }                                                                  \
        }                                                                      \
        __builtin_amdgcn_s_setprio(0);                                         \
    }

__global__ __launch_bounds__(256, 2) void k_attn8(const short* __restrict__ qkv,
                                                  short* __restrict__ att) {
    __shared__ short Ks[2][64 * 128];
    __shared__ short Vs[2][96 * 64];
    const int tid = threadIdx.x, lane = tid & 63, wid = tid >> 6;
    const int lq = lane & 31, hi = lane >> 5;
    const int L = blockIdx.x;
    const int h = L & 7, bx = (L >> 3) & 7, b = L >> 6;
    const short* base = qkv + (size_t)b * 2048 * 2304 + h * 96;
    const short* Kb = base + 768;
    const short* Vb = base + 1536;
    const int vkvr = (tid / 12) * 4, vd0 = (tid % 12) * 8;
    const int vslot = (vkvr & ~12) | ((vkvr & 4) << 1) | ((vkvr & 8) >> 1);
    bf16x8 vreg[4];
    const float QSC = 0.14724445f; // log2(e)/sqrt(96)

    auto stageK = [&](int jt, int bb) {
        const int kv0 = jt * 64;
        for (int c = wid; c < 16; c += 4) {
            const int dl = c * 1024 + lane * 16;
            const int row = dl >> 8;
            const int scol = (dl & 255) ^ ((row & 7) << 4);
            __builtin_amdgcn_global_load_lds(GLB_AS(Kb + (size_t)(kv0 + row) * 2304 + (scol >> 1)),
                                             LDS_AS(&Ks[bb][c * 512]), 16, 0, 0);
        }
    };
    auto loadV = [&](int jt) {
        if (tid < 192) {
            const int kv0 = jt * 64;
            #pragma unroll
            for (int e = 0; e < 4; ++e)
                vreg[e] = *(const bf16x8*)(Vb + (size_t)(kv0 + vkvr + e) * 2304 + vd0);
        }
    };
    auto writeV = [&](int bb) {
        if (tid < 192) {
            #pragma unroll
            for (int f = 0; f < 8; ++f) {
                const int row = vd0 + f;
                const int sw = ((row & 7) ^ ((row >> 3) & 7)) << 4;
                const int byte = (row * 128 + vslot * 2) ^ sw;
                bf16x4 w4;
                w4[0] = vreg[0][f]; w4[1] = vreg[1][f]; w4[2] = vreg[2][f]; w4[3] = vreg[3][f];
                *(bf16x4*)((char*)&Vs[bb][0] + byte) = w4;
            }
        }
    };

    const int qtH = 15 - bx, qtL = bx;
    const int q0H = qtH * 128 + wid * 32, q0L = qtL * 128 + wid * 32;
    const int qaH = q0H + lq, qaL = q0L + lq;

    bf16x8 qfH[6], qfL[6];
    #pragma unroll
    for (int kb = 0; kb < 6; ++kb) {
        bf16x8 vH = *(const bf16x8*)(base + (size_t)qaH * 2304 + kb * 16 + hi * 8);
        bf16x8 vL = *(const bf16x8*)(base + (size_t)qaL * 2304 + kb * 16 + hi * 8);
        #pragma unroll
        for (int e = 0; e < 8; ++e) {
            qfH[kb][e] = f2bf(bf2f(vH[e]) * QSC);
            qfL[kb][e] = f2bf(bf2f(vL[e]) * QSC);
        }
    }

    f32x16 oH[3] = {}, oL[3] = {};
    float lrowH = 0.f, lrowL = 0.f;
    const int nt = 2 * qtH + 2;

    stageK(0, 0);
    loadV(0);
    asm volatile("s_waitcnt vmcnt(0)" ::: "memory");
    writeV(0);
    __syncthreads();

    int cur = 0;
    for (int jt = 0; jt < nt; ++jt) {
        const int nxt = cur ^ 1;
        const bool more = (jt + 1 < nt);
        if (more) { stageK(jt + 1, nxt); loadV(jt + 1); }

        const int kv0 = jt * 64;
        ATTN_PROC(qfH, oH, lrowH, qaH, q0H)
        ATTN_PROC(qfL, oL, lrowL, qaL, q0L)

        if (more) {
            asm volatile("s_waitcnt vmcnt(0)" ::: "memory");
            writeV(nxt);
        }
        __syncthreads();
        cur = nxt;
    }

    {
        const float inv = 1.f / lrowH;
        short* orow = att + (size_t)((size_t)b * 2048 + qaH) * 768 + h * 96;
        #pragma unroll
        for (int db = 0; db < 3; ++db)
            #pragma unroll
            for (int j = 0; j < 4; ++j) {
                bf16x4 ov;
                #pragma unroll
                for (int e = 0; e < 4; ++e) ov[e] = f2bf(oH[db][4 * j + e] * inv);
                *(bf16x4*)(orow + db * 32 + 8 * j + 4 * hi) = ov;
            }
    }
    {
        const float inv = 1.f / lrowL;
        short* orow = att + (size_t)((size_t)b * 2048 + qaL) * 768 + h * 96;
        #pragma unroll
        for (int db = 0; db < 3; ++db)
            #pragma unroll
            for (int j = 0; j < 4; ++j) {
                bf16x4 ov;
                #pragma unroll
                for (int e = 0; e < 4; ++e) ov[e] = f2bf(oL[db][4 * j + e] * inv);
                *(bf16x4*)(orow + db * 32 + 8 * j + 4 * hi) = ov;
            }
    }
}

// ---------------- launcher ----------------
extern "C" void kernel_launch(void* const* d_in, const int* in_sizes, int n_in,
                              void* d_out, int out_size, void* d_ws, size_t ws_size,
                              hipStream_t stream) {
    (void)in_sizes; (void)n_in; (void)out_size; (void)ws_size;
    const float* x      = (const float*)d_in[0];
    const float* ln1_w  = (const float*)d_in[1];
    const float* ln1_b  = (const float*)d_in[2];
    const float* w_qkv  = (const float*)d_in[3];
    const float* b_qkv  = (const float*)d_in[4];
    const float* w_proj = (const float*)d_in[5];
    const float* b_proj = (const float*)d_in[6];
    const float* ln2_w  = (const float*)d_in[7];
    const float* ln2_b  = (const float*)d_in[8];
    const float* w_fc   = (const float*)d_in[9];
    const float* b_fc   = (const float*)d_in[10];
    const float* w_mlp  = (const float*)d_in[11];
    const float* b_mlp  = (const float*)d_in[12];

    const int C = 768, M = 8 * 2048;

    char* ws = (char*)d_ws;
    size_t off = 0;
    auto alloc = [&](size_t bytes) {
        char* p = ws + off;
        off += (bytes + 255) & ~(size_t)255;
        return p;
    };
    short* wqkv_b = (short*)alloc((size_t)3 * C * C * 2);
    short* wproj_b = (short*)alloc((size_t)C * C * 2);
    short* wfc_b  = (short*)alloc((size_t)4 * C * C * 2);
    short* wmlp_b = (short*)alloc((size_t)4 * C * C * 2);
    short* bufA   = (short*)alloc((size_t)M * C * 2);
    short* bufB   = (short*)alloc((size_t)M * 4 * C * 2);
    short* x2b    = (short*)alloc((size_t)M * C * 2);   // residual in bf16

    // fused LN1 + weight casts
    k_prep<<<dim3(M), dim3(256), 0, stream>>>(
        x, ln1_w, ln1_b, bufA,
        w_qkv, w_proj, w_fc, w_mlp, wqkv_b, wproj_b, wfc_b, wmlp_b,
        3 * C * C / 4, C * C / 4, 4 * C * C / 4, 4 * C * C / 4);

    // qkv: N=2304, BN=192 -> 768 blocks (3 exact rounds)
    k_gemm256<0, 3><<<dim3(2304 / 192, M / 256), dim3(512), 0, stream>>>(
        bufA, wqkv_b, b_qkv, nullptr, bufB, M, 2304, C);
    k_attn8<<<dim3(512), dim3(256), 0, stream>>>(bufB, bufA);
    // attn-proj: x2b(bf16) = x(f32) + att @ W^T + b ; 256 blocks (1 round)
    k_gemm256<3, 3><<<dim3(768 / 192, M / 256), dim3(512), 0, stream>>>(
        bufA, wproj_b, b_proj, x, x2b, M, C, C);
    k_layernorm_bf<<<dim3(M), dim3(256), 0, stream>>>(x2b, ln2_w, ln2_b, bufA);
    // fc: N=3072, BN=384 -> 512 blocks (2 exact rounds)
    k_gemm384<2><<<dim3(3072 / 384, M / 256), dim3(512), 0, stream>>>(
        bufA, wfc_b, b_fc, nullptr, bufB, M, 3072, C);
    // mlp-proj: d_out(f32) = x2b(bf16) + h @ W^T + b ; 256 blocks (1 round)
    k_gemm256<4, 3><<<dim3(768 / 192, M / 256), dim3(512), 0, stream>>>(
        bufB, wmlp_b, b_mlp, x2b, d_out, M, C, 4 * C);
}

// Round 17
// 411.280 us; speedup vs baseline: 1.2462x; 1.2462x over previous
//
#include <hip/hip_runtime.h>
#include <hip/hip_bf16.h>
#include <cstdint>
#include <cstddef>

typedef __attribute__((ext_vector_type(8))) short bf16x8;
typedef __attribute__((ext_vector_type(4))) short bf16x4;
typedef __attribute__((ext_vector_type(4))) float f32x4;
typedef __attribute__((ext_vector_type(16))) float f32x16;

#define GLB_AS(p) ((const __attribute__((address_space(1))) void*)(p))
#define LDS_AS(p) ((__attribute__((address_space(3))) void*)(p))

__device__ __forceinline__ short f2bf(float f) {
    union { float f; unsigned u; } x; x.f = f;
    unsigned r = (x.u + 0x7fffu + ((x.u >> 16) & 1u)) >> 16;
    return (short)r;
}
__device__ __forceinline__ float bf2f(short s) {
    union { unsigned u; float f; } x;
    x.u = ((unsigned)(unsigned short)s) << 16;
    return x.f;
}
__device__ __forceinline__ unsigned packbf2(float a, float b) {
    union { float f; unsigned u; } x, y; x.f = a; y.f = b;
    return (x.u >> 16) | (y.u & 0xffff0000u);
}
__device__ __forceinline__ f32x4 MF(bf16x8 a, bf16x8 b, f32x4 c) {
    return __builtin_amdgcn_mfma_f32_16x16x32_bf16(a, b, c, 0, 0, 0);
}
__device__ __forceinline__ f32x16 MF32(bf16x8 a, bf16x8 b, f32x16 c) {
    return __builtin_amdgcn_mfma_f32_32x32x16_bf16(a, b, c, 0, 0, 0);
}

// ---------------- fused: LN1 (one row/block) + weight-cast slice ----------------
__global__ __launch_bounds__(256) void k_prep(const float* __restrict__ x,
                                              const float* __restrict__ ln1_w,
                                              const float* __restrict__ ln1_b,
                                              short* __restrict__ xhat,
                                              const float* __restrict__ s0,
                                              const float* __restrict__ s1,
                                              const float* __restrict__ s2,
                                              const float* __restrict__ s3,
                                              short* __restrict__ d0,
                                              short* __restrict__ d1,
                                              short* __restrict__ d2,
                                              short* __restrict__ d3,
                                              int n0, int n1, int n2, int n3) {
    const int row = blockIdx.x;
    const int tid = threadIdx.x;
    {
        const float* xr = x + (size_t)row * 768;
        float v0 = xr[tid], v1 = xr[tid + 256], v2 = xr[tid + 512];
        float s = v0 + v1 + v2;
        float ss = v0 * v0 + v1 * v1 + v2 * v2;
        #pragma unroll
        for (int m = 32; m; m >>= 1) { s += __shfl_xor(s, m); ss += __shfl_xor(ss, m); }
        __shared__ float red[8];
        int wid = tid >> 6, lane = tid & 63;
        if (lane == 0) { red[wid] = s; red[4 + wid] = ss; }
        __syncthreads();
        s = red[0] + red[1] + red[2] + red[3];
        ss = red[4] + red[5] + red[6] + red[7];
        float mean = s * (1.f / 768.f);
        float var = ss * (1.f / 768.f) - mean * mean;
        float inv = rsqrtf(var + 1e-5f);
        short* orow = xhat + (size_t)row * 768;
        orow[tid]       = f2bf((v0 - mean) * inv * ln1_w[tid]       + ln1_b[tid]);
        orow[tid + 256] = f2bf((v1 - mean) * inv * ln1_w[tid + 256] + ln1_b[tid + 256]);
        orow[tid + 512] = f2bf((v2 - mean) * inv * ln1_w[tid + 512] + ln1_b[tid + 512]);
    }
    const int total = n0 + n1 + n2 + n3;
    const int stride = gridDim.x * 256;
    for (int i = blockIdx.x * 256 + tid; i < total; i += stride) {
        int j = i;
        const float* s; short* d;
        if (j < n0) { s = s0; d = d0; }
        else {
            j -= n0;
            if (j < n1) { s = s1; d = d1; }
            else {
                j -= n1;
                if (j < n2) { s = s2; d = d2; }
                else { j -= n2; s = s3; d = d3; }
            }
        }
        float4 v = ((const float4*)s)[j];
        bf16x4 o;
        o[0] = f2bf(v.x); o[1] = f2bf(v.y); o[2] = f2bf(v.z); o[3] = f2bf(v.w);
        ((bf16x4*)d)[j] = o;
    }
}

// ---------------- LayerNorm on bf16 input (x2) -> bf16 ----------------
__global__ __launch_bounds__(256) void k_layernorm_bf(const short* __restrict__ xb,
                                                      const float* __restrict__ w,
                                                      const float* __restrict__ b,
                                                      short* __restrict__ out) {
    const int row = blockIdx.x;
    const int tid = threadIdx.x;
    float v[4] = {0.f, 0.f, 0.f, 0.f};
    if (tid < 192) {
        bf16x4 raw = ((const bf16x4*)(xb + (size_t)row * 768))[tid];
        #pragma unroll
        for (int j = 0; j < 4; ++j) v[j] = bf2f(raw[j]);
    }
    float s = v[0] + v[1] + v[2] + v[3];
    float ss = v[0] * v[0] + v[1] * v[1] + v[2] * v[2] + v[3] * v[3];
    #pragma unroll
    for (int m = 32; m; m >>= 1) { s += __shfl_xor(s, m); ss += __shfl_xor(ss, m); }
    __shared__ float red[8];
    int wid = tid >> 6, lane = tid & 63;
    if (lane == 0) { red[wid] = s; red[4 + wid] = ss; }
    __syncthreads();
    s = red[0] + red[1] + red[2] + red[3];
    ss = red[4] + red[5] + red[6] + red[7];
    float mean = s * (1.f / 768.f);
    float var = ss * (1.f / 768.f) - mean * mean;
    float inv = rsqrtf(var + 1e-5f);
    if (tid < 192) {
        float4 wv = ((const float4*)w)[tid];
        float4 bv = ((const float4*)b)[tid];
        bf16x4 o;
        o[0] = f2bf((v[0] - mean) * inv * wv.x + bv.x);
        o[1] = f2bf((v[1] - mean) * inv * wv.y + bv.y);
        o[2] = f2bf((v[2] - mean) * inv * wv.z + bv.z);
        o[3] = f2bf((v[3] - mean) * inv * wv.w + bv.w);
        ((bf16x4*)(out + (size_t)row * 768))[tid] = o;
    }
}

// ============ 256 x (NFR*64) GEMM (16x16 MFMA), R11-proven schedule ============
// EPI 0: bf16 = acc+bias | 2: bf16 gelu(acc+bias) | 3: bf16 = acc+bias+f32res
// EPI 4: f32 = acc+bias+bf16res
template <int EPI, int NFR>
__global__ __launch_bounds__(512, 2) void k_gemm256(const short* __restrict__ A,
                                                    const short* __restrict__ B,
                                                    const float* __restrict__ bias,
                                                    const void* __restrict__ res,
                                                    void* __restrict__ out,
                                                    int M, int N, int K) {
    __shared__ short As2[2][256 * 64];
    __shared__ short Bs2[2][NFR * 64 * 64];
    const int tid = threadIdx.x, lane = tid & 63, wid = tid >> 6;
    const int l4 = lane & 15, lh = lane >> 4;
    const int wm = wid >> 2, wn = wid & 3;
    const int gx = gridDim.x;
    const int nwg = gx * gridDim.y;
    int wg = blockIdx.y * gx + blockIdx.x;
    { const int q = nwg >> 3; wg = (wg & 7) * q + (wg >> 3); }   // nwg % 8 == 0
    const int row0 = (wg / gx) * 256, col0 = (wg % gx) * (NFR * 64);

    auto stageA = [&](short* lds, int mh, int k0) {
        #pragma unroll
        for (int i = 0; i < 2; ++i) {
            const int chunk = wid * 2 + i;
            const int dl = mh * 16384 + chunk * 1024 + lane * 16;
            const int r = dl >> 7;
            const int cb = (dl & 127) ^ ((r & 7) << 4);
            __builtin_amdgcn_global_load_lds(
                GLB_AS(A + (size_t)(row0 + r) * K + k0 + (cb >> 1)),
                LDS_AS(lds + mh * 8192 + chunk * 512), 16, 0, 0);
        }
    };
    auto stageB = [&](short* lds, int k0) {
        #pragma unroll
        for (int i = 0; i < NFR; ++i) {
            const int chunk = wid * NFR + i;
            const int dl = chunk * 1024 + lane * 16;
            const int r = dl >> 7;
            const int cb = (dl & 127) ^ ((r & 7) << 4);
            __builtin_amdgcn_global_load_lds(
                GLB_AS(B + (size_t)(col0 + r) * K + k0 + (cb >> 1)),
                LDS_AS(lds + chunk * 512), 16, 0, 0);
        }
    };
    auto rd = [&](const short* lds, int r, int kb) -> bf16x8 {
        return *(const bf16x8*)((const char*)lds + r * 128 +
                                ((kb * 64 + lh * 16) ^ ((r & 7) << 4)));
    };

    f32x4 acc[8][NFR] = {};
    bf16x8 a[4][2], b0[2][2], b1[2][2];
    const int NT = K >> 6;

    stageA(As2[0], 0, 0);
    stageA(As2[0], 1, 0);
    stageB(Bs2[0], 0);
    asm volatile("s_waitcnt vmcnt(0)" ::: "memory");
    __builtin_amdgcn_s_barrier();

    for (int t = 0; t < NT; ++t) {
        const int cur = t & 1, nxt = cur ^ 1;
        const short* Ac = As2[cur];
        const short* Bc = Bs2[cur];
        const int kn = (t + 1) << 6;
        const bool more = (t + 1 < NT);
        #pragma unroll
        for (int mi = 0; mi < 4; ++mi) {
            const int r = wm * 128 + mi * 16 + l4;
            a[mi][0] = rd(Ac, r, 0); a[mi][1] = rd(Ac, r, 1);
        }
        #pragma unroll
        for (int ni = 0; ni < 2; ++ni) {
            const int r = wn * (NFR * 16) + ni * 16 + l4;
            b0[ni][0] = rd(Bc, r, 0); b0[ni][1] = rd(Bc, r, 1);
        }
        if (more) { stageA(As2[nxt], 0, kn); stageA(As2[nxt], 1, kn); }
        __builtin_amdgcn_s_setprio(1);
        #pragma unroll
        for (int mi = 0; mi < 4; ++mi)
            #pragma unroll
            for (int ni = 0; ni < 2; ++ni) {
                acc[mi][ni] = MF(a[mi][0], b0[ni][0], acc[mi][ni]);
                acc[mi][ni] = MF(a[mi][1], b0[ni][1], acc[mi][ni]);
            }
        __builtin_amdgcn_s_setprio(0);
        __builtin_amdgcn_s_barrier();
        #pragma unroll
        for (int j = 0; j < NFR - 2; ++j) {
            const int r = wn * (NFR * 16) + (2 + j) * 16 + l4;
            b1[j][0] = rd(Bc, r, 0); b1[j][1] = rd(Bc, r, 1);
        }
        if (more) stageB(Bs2[nxt], kn);
        __builtin_amdgcn_s_setprio(1);
        #pragma unroll
        for (int mi = 0; mi < 4; ++mi)
            #pragma unroll
            for (int j = 0; j < NFR - 2; ++j) {
                acc[mi][2 + j] = MF(a[mi][0], b1[j][0], acc[mi][2 + j]);
                acc[mi][2 + j] = MF(a[mi][1], b1[j][1], acc[mi][2 + j]);
            }
        __builtin_amdgcn_s_setprio(0);
        __builtin_amdgcn_s_barrier();
        #pragma unroll
        for (int mi = 0; mi < 4; ++mi) {
            const int r = wm * 128 + (4 + mi) * 16 + l4;
            a[mi][0] = rd(Ac, r, 0); a[mi][1] = rd(Ac, r, 1);
        }
        __builtin_amdgcn_s_setprio(1);
        #pragma unroll
        for (int mi = 0; mi < 4; ++mi)
            #pragma unroll
            for (int j = 0; j < NFR - 2; ++j) {
                acc[4 + mi][2 + j] = MF(a[mi][0], b1[j][0], acc[4 + mi][2 + j]);
                acc[4 + mi][2 + j] = MF(a[mi][1], b1[j][1], acc[4 + mi][2 + j]);
            }
        __builtin_amdgcn_s_setprio(0);
        __builtin_amdgcn_s_barrier();
        __builtin_amdgcn_s_setprio(1);
        #pragma unroll
        for (int mi = 0; mi < 4; ++mi)
            #pragma unroll
            for (int ni = 0; ni < 2; ++ni) {
                acc[4 + mi][ni] = MF(a[mi][0], b0[ni][0], acc[4 + mi][ni]);
                acc[4 + mi][ni] = MF(a[mi][1], b0[ni][1], acc[4 + mi][ni]);
            }
        __builtin_amdgcn_s_setprio(0);
        if (more) asm volatile("s_waitcnt vmcnt(0)" ::: "memory");
        __builtin_amdgcn_s_barrier();
    }

    #pragma unroll
    for (int mi = 0; mi < 8; ++mi) {
        const int rowb = row0 + wm * 128 + mi * 16 + lh * 4;
        #pragma unroll
        for (int ni = 0; ni < NFR; ++ni) {
            const int col = col0 + wn * (NFR * 16) + ni * 16 + l4;
            const float bv = bias[col];
            #pragma unroll
            for (int j = 0; j < 4; ++j) {
                const size_t idx = (size_t)(rowb + j) * N + col;
                float v = acc[mi][ni][j] + bv;
                if (EPI == 0) {
                    ((short*)out)[idx] = f2bf(v);
                } else if (EPI == 2) {
                    float u = v + 0.044715f * v * v * v;
                    float t = 1.f - 2.f / (__expf(1.5957691216f * u) + 1.f);
                    ((short*)out)[idx] = f2bf(0.5f * v * (1.f + t));
                } else if (EPI == 3) {
                    ((short*)out)[idx] = f2bf(v + ((const float*)res)[idx]);
                } else { // EPI == 4
                    ((float*)out)[idx] = v + bf2f(((const short*)res)[idx]);
                }
            }
        }
    }
}

// ---------------- causal flash attention v8: merged q-tile pair (R11) ----------
#define ATTN_PROC(QF, O, LROW, QA, Q0)                                         \
    if (kv0 <= (Q0) + 31) {                                                    \
        const bool full = (kv0 + 63 <= (Q0));                                  \
        f32x16 s0 = {}, s1 = {};                                               \
        __builtin_amdgcn_s_setprio(1);                                         \
        _Pragma("unroll")                                                      \
        for (int kb = 0; kb < 6; ++kb) {                                       \
            const int r0 = lq, r1 = 32 + lq;                                   \
            bf16x8 kf0 = *(const bf16x8*)((const char*)&Ks[cur][0] +           \
                          r0 * 256 + ((kb * 32 + hi * 16) ^ ((r0 & 7) << 4))); \
            bf16x8 kf1 = *(const bf16x8*)((const char*)&Ks[cur][0] +           \
                          r1 * 256 + ((kb * 32 + hi * 16) ^ ((r1 & 7) << 4))); \
            s0 = MF32(kf0, QF[kb], s0);                                        \
            s1 = MF32(kf1, QF[kb], s1);                                        \
        }                                                                      \
        __builtin_amdgcn_s_setprio(0);                                         \
        if (!full) {                                                           \
            _Pragma("unroll")                                                  \
            for (int r = 0; r < 16; ++r) {                                     \
                const int kvl = (r & 3) + 8 * (r >> 2) + 4 * hi;               \
                if (kv0 + kvl > (QA)) s0[r] = -INFINITY;                       \
                if (kv0 + 32 + kvl > (QA)) s1[r] = -INFINITY;                  \
            }                                                                  \
        }                                                                      \
        _Pragma("unroll")                                                      \
        for (int r = 0; r < 16; ++r) { s0[r] = exp2f(s0[r]); s1[r] = exp2f(s1[r]); } \
        float ar[16];                                                          \
        _Pragma("unroll")                                                      \
        for (int r = 0; r < 16; ++r) ar[r] = s0[r] + s1[r];                    \
        _Pragma("unroll")                                                      \
        for (int st = 8; st; st >>= 1)                                         \
            _Pragma("unroll")                                                  \
            for (int r = 0; r < 8; ++r)                                        \
                if (r < st) ar[r] += ar[r + st];                               \
        (LROW) += ar[0] + __shfl_xor(ar[0], 32);                               \
        unsigned pk0[8], pk1[8];                                               \
        _Pragma("unroll")                                                      \
        for (int j = 0; j < 8; ++j) {                                          \
            pk0[j] = packbf2(s0[2 * j], s0[2 * j + 1]);                        \
            pk1[j] = packbf2(s1[2 * j], s1[2 * j + 1]);                        \
        }                                                                      \
        __builtin_amdgcn_s_setprio(1);                                         \
        _Pragma("unroll")                                                      \
        for (int db = 0; db < 3; ++db) {                                       \
            const int vrow = db * 32 + lq;                                     \
            const int vsw = ((vrow & 7) ^ ((vrow >> 3) & 7)) << 4;             \
            _Pragma("unroll")                                                  \
            for (int c = 0; c < 4; ++c) {                                      \
                bf16x8 vf = *(const bf16x8*)((const char*)&Vs[cur][0] +        \
                             vrow * 128 + ((c * 32 + hi * 16) ^ vsw));         \
                union { unsigned u[4]; bf16x8 v; } pa;                         \
                const unsigned* pk = (c < 2) ? pk0 : pk1;                      \
                const int o4 = (c & 1) * 4;                                    \
                pa.u[0] = pk[o4]; pa.u[1] = pk[o4 + 1];                        \
                pa.u[2] = pk[o4 + 2]; pa.u[3] = pk[o4 + 3];                    \
                (O)[db] = MF32(vf, pa.v, (O)[db]);                             \
            }                                                                  \
        }                                                                      \
        __builtin_amdgcn_s_setprio(0);                                         \
    }

__global__ __launch_bounds__(256, 2) void k_attn8(const short* __restrict__ qkv,
                                                  short* __restrict__ att) {
    __shared__ short Ks[2][64 * 128];
    __shared__ short Vs[2][96 * 64];
    const int tid = threadIdx.x, lane = tid & 63, wid = tid >> 6;
    const int lq = lane & 31, hi = lane >> 5;
    const int L = blockIdx.x;
    const int h = L & 7, bx = (L >> 3) & 7, b = L >> 6;
    const short* base = qkv + (size_t)b * 2048 * 2304 + h * 96;
    const short* Kb = base + 768;
    const short* Vb = base + 1536;
    const int vkvr = (tid / 12) * 4, vd0 = (tid % 12) * 8;
    const int vslot = (vkvr & ~12) | ((vkvr & 4) << 1) | ((vkvr & 8) >> 1);
    bf16x8 vreg[4];
    const float QSC = 0.14724445f; // log2(e)/sqrt(96)

    auto stageK = [&](int jt, int bb) {
        const int kv0 = jt * 64;
        for (int c = wid; c < 16; c += 4) {
            const int dl = c * 1024 + lane * 16;
            const int row = dl >> 8;
            const int scol = (dl & 255) ^ ((row & 7) << 4);
            __builtin_amdgcn_global_load_lds(GLB_AS(Kb + (size_t)(kv0 + row) * 2304 + (scol >> 1)),
                                             LDS_AS(&Ks[bb][c * 512]), 16, 0, 0);
        }
    };
    auto loadV = [&](int jt) {
        if (tid < 192) {
            const int kv0 = jt * 64;
            #pragma unroll
            for (int e = 0; e < 4; ++e)
                vreg[e] = *(const bf16x8*)(Vb + (size_t)(kv0 + vkvr + e) * 2304 + vd0);
        }
    };
    auto writeV = [&](int bb) {
        if (tid < 192) {
            #pragma unroll
            for (int f = 0; f < 8; ++f) {
                const int row = vd0 + f;
                const int sw = ((row & 7) ^ ((row >> 3) & 7)) << 4;
                const int byte = (row * 128 + vslot * 2) ^ sw;
                bf16x4 w4;
                w4[0] = vreg[0][f]; w4[1] = vreg[1][f]; w4[2] = vreg[2][f]; w4[3] = vreg[3][f];
                *(bf16x4*)((char*)&Vs[bb][0] + byte) = w4;
            }
        }
    };

    const int qtH = 15 - bx, qtL = bx;
    const int q0H = qtH * 128 + wid * 32, q0L = qtL * 128 + wid * 32;
    const int qaH = q0H + lq, qaL = q0L + lq;

    bf16x8 qfH[6], qfL[6];
    #pragma unroll
    for (int kb = 0; kb < 6; ++kb) {
        bf16x8 vH = *(const bf16x8*)(base + (size_t)qaH * 2304 + kb * 16 + hi * 8);
        bf16x8 vL = *(const bf16x8*)(base + (size_t)qaL * 2304 + kb * 16 + hi * 8);
        #pragma unroll
        for (int e = 0; e < 8; ++e) {
            qfH[kb][e] = f2bf(bf2f(vH[e]) * QSC);
            qfL[kb][e] = f2bf(bf2f(vL[e]) * QSC);
        }
    }

    f32x16 oH[3] = {}, oL[3] = {};
    float lrowH = 0.f, lrowL = 0.f;
    const int nt = 2 * qtH + 2;

    stageK(0, 0);
    loadV(0);
    asm volatile("s_waitcnt vmcnt(0)" ::: "memory");
    writeV(0);
    __syncthreads();

    int cur = 0;
    for (int jt = 0; jt < nt; ++jt) {
        const int nxt = cur ^ 1;
        const bool more = (jt + 1 < nt);
        if (more) { stageK(jt + 1, nxt); loadV(jt + 1); }

        const int kv0 = jt * 64;
        ATTN_PROC(qfH, oH, lrowH, qaH, q0H)
        ATTN_PROC(qfL, oL, lrowL, qaL, q0L)

        if (more) {
            asm volatile("s_waitcnt vmcnt(0)" ::: "memory");
            writeV(nxt);
        }
        __syncthreads();
        cur = nxt;
    }

    {
        const float inv = 1.f / lrowH;
        short* orow = att + (size_t)((size_t)b * 2048 + qaH) * 768 + h * 96;
        #pragma unroll
        for (int db = 0; db < 3; ++db)
            #pragma unroll
            for (int j = 0; j < 4; ++j) {
                bf16x4 ov;
                #pragma unroll
                for (int e = 0; e < 4; ++e) ov[e] = f2bf(oH[db][4 * j + e] * inv);
                *(bf16x4*)(orow + db * 32 + 8 * j + 4 * hi) = ov;
            }
    }
    {
        const float inv = 1.f / lrowL;
        short* orow = att + (size_t)((size_t)b * 2048 + qaL) * 768 + h * 96;
        #pragma unroll
        for (int db = 0; db < 3; ++db)
            #pragma unroll
            for (int j = 0; j < 4; ++j) {
                bf16x4 ov;
                #pragma unroll
                for (int e = 0; e < 4; ++e) ov[e] = f2bf(oL[db][4 * j + e] * inv);
                *(bf16x4*)(orow + db * 32 + 8 * j + 4 * hi) = ov;
            }
    }
}

// ---------------- launcher ----------------
extern "C" void kernel_launch(void* const* d_in, const int* in_sizes, int n_in,
                              void* d_out, int out_size, void* d_ws, size_t ws_size,
                              hipStream_t stream) {
    (void)in_sizes; (void)n_in; (void)out_size; (void)ws_size;
    const float* x      = (const float*)d_in[0];
    const float* ln1_w  = (const float*)d_in[1];
    const float* ln1_b  = (const float*)d_in[2];
    const float* w_qkv  = (const float*)d_in[3];
    const float* b_qkv  = (const float*)d_in[4];
    const float* w_proj = (const float*)d_in[5];
    const float* b_proj = (const float*)d_in[6];
    const float* ln2_w  = (const float*)d_in[7];
    const float* ln2_b  = (const float*)d_in[8];
    const float* w_fc   = (const float*)d_in[9];
    const float* b_fc   = (const float*)d_in[10];
    const float* w_mlp  = (const float*)d_in[11];
    const float* b_mlp  = (const float*)d_in[12];

    const int C = 768, M = 8 * 2048;

    char* ws = (char*)d_ws;
    size_t off = 0;
    auto alloc = [&](size_t bytes) {
        char* p = ws + off;
        off += (bytes + 255) & ~(size_t)255;
        return p;
    };
    short* wqkv_b = (short*)alloc((size_t)3 * C * C * 2);
    short* wproj_b = (short*)alloc((size_t)C * C * 2);
    short* wfc_b  = (short*)alloc((size_t)4 * C * C * 2);
    short* wmlp_b = (short*)alloc((size_t)4 * C * C * 2);
    short* bufA   = (short*)alloc((size_t)M * C * 2);
    short* bufB   = (short*)alloc((size_t)M * 4 * C * 2);
    short* x2b    = (short*)alloc((size_t)M * C * 2);   // residual in bf16

    // fused LN1 + weight casts
    k_prep<<<dim3(M), dim3(256), 0, stream>>>(
        x, ln1_w, ln1_b, bufA,
        w_qkv, w_proj, w_fc, w_mlp, wqkv_b, wproj_b, wfc_b, wmlp_b,
        3 * C * C / 4, C * C / 4, 4 * C * C / 4, 4 * C * C / 4);

    // qkv: N=2304, BN=192 -> 768 blocks (3 exact rounds)
    k_gemm256<0, 3><<<dim3(2304 / 192, M / 256), dim3(512), 0, stream>>>(
        bufA, wqkv_b, b_qkv, nullptr, bufB, M, 2304, C);
    k_attn8<<<dim3(512), dim3(256), 0, stream>>>(bufB, bufA);
    // attn-proj: x2b(bf16) = x(f32) + att @ W^T + b ; 256 blocks (1 round)
    k_gemm256<3, 3><<<dim3(768 / 192, M / 256), dim3(512), 0, stream>>>(
        bufA, wproj_b, b_proj, x, x2b, M, C, C);
    k_layernorm_bf<<<dim3(M), dim3(256), 0, stream>>>(x2b, ln2_w, ln2_b, bufA);
    // fc: N=3072, BN=256 -> 768 blocks (3 exact rounds)
    k_gemm256<2, 4><<<dim3(3072 / 256, M / 256), dim3(512), 0, stream>>>(
        bufA, wfc_b, b_fc, nullptr, bufB, M, 3072, C);
    // mlp-proj: d_out(f32) = x2b(bf16) + h @ W^T + b ; 256 blocks (1 round)
    k_gemm256<4, 3><<<dim3(768 / 192, M / 256), dim3(512), 0, stream>>>(
        bufB, wmlp_b, b_mlp, x2b, d_out, M, C, 4 * C);
}